// Round 8
// baseline (1050.020 us; speedup 1.0000x reference)
//
#include <hip/hip_runtime.h>
#include <hip/hip_bf16.h>

#define IN_CH 256
#define OUT_CH 64
#define SCAN_CHUNK 1024   // elements per scan block (256 threads x 4)
#define NGROUP 8          // one row-group per XCD
#define ECHUNK 1024       // edges per work-ticket (256 thr x 4)

typedef int   int4v   __attribute__((ext_vector_type(4)));
typedef float float4v __attribute__((ext_vector_type(4)));

// ---- bf16 helpers (RNE) ----
__device__ __forceinline__ unsigned short f2bf(float f) {
    unsigned u = __float_as_uint(f);
    u += 0x7fff + ((u >> 16) & 1);
    return (unsigned short)(u >> 16);
}
__device__ __forceinline__ float bf2f(unsigned short h) {
    return __uint_as_float((unsigned)h << 16);
}
__device__ __forceinline__ unsigned read_xcc_id() {
    unsigned x;
    asm volatile("s_getreg_b32 %0, hwreg(HW_REG_XCC_ID)" : "=s"(x));
    return x & (NGROUP - 1);
}

using bfrag = __attribute__((ext_vector_type(8))) short;   // 8 bf16 (4 VGPRs)
using ffrag = __attribute__((ext_vector_type(4))) float;   // 4 fp32 acc

// pack 8 fp32 -> 8 bf16 via v_cvt_pk_bf16_f32 (4 instructions)
__device__ __forceinline__ bfrag pack8(float4 a, float4 b) {
    union { bfrag s; __hip_bfloat162 h[4]; } u;
    u.h[0] = __float22bfloat162_rn(make_float2(a.x, a.y));
    u.h[1] = __float22bfloat162_rn(make_float2(a.z, a.w));
    u.h[2] = __float22bfloat162_rn(make_float2(b.x, b.y));
    u.h[3] = __float22bfloat162_rn(make_float2(b.z, b.w));
    return u.s;
}

// ---------------------------------------------------------------------------
// MFMA dense transform: B0[n][64] = bf16(relu(feat @ W + bias))
// 128 rows/block (4 waves x 2 M-tiles), K=256 in 8 steps of 32.
// Fragment-major LDS W (conflict-optimal lane*16B ds_read_b128).
// Layouts (R6/R7-verified): A[m=lane&15][k=quad*8+j], B[k=quad*8+j][n=lane&15],
// C/D row=quad*4+r col=lane&15.
// ---------------------------------------------------------------------------
__global__ __launch_bounds__(256) void gemm_mfma_kernel(
    const float* __restrict__ feat, const float* __restrict__ W,
    const float* __restrict__ bias, unsigned short* __restrict__ out, int n)
{
    __shared__ unsigned short Wl[IN_CH * OUT_CH];   // 32 KB

    for (int i = threadIdx.x; i < IN_CH * OUT_CH; i += 256) {
        int k  = i >> 6;          // 0..255
        int c  = i & 63;          // 0..63
        int ks = k >> 5;
        int kq = (k >> 3) & 3;
        int j  = k & 7;
        int nt = c >> 4;
        int lc = c & 15;
        Wl[(((ks * 4 + nt) * 64) + kq * 16 + lc) * 8 + j] = f2bf(W[i]);
    }
    __syncthreads();

    const int wv   = threadIdx.x >> 6;
    const int lane = threadIdx.x & 63;
    const int quad = lane >> 4;
    const int lc   = lane & 15;

    const int rowbase = blockIdx.x * 128 + wv * 32;
    const float4* frowA = (const float4*)(feat + (size_t)min(rowbase + lc,      n - 1) * IN_CH);
    const float4* frowB = (const float4*)(feat + (size_t)min(rowbase + 16 + lc, n - 1) * IN_CH);

    ffrag acc[2][4];
#pragma unroll
    for (int mt = 0; mt < 2; ++mt)
#pragma unroll
        for (int nt = 0; nt < 4; ++nt)
#pragma unroll
            for (int r = 0; r < 4; ++r) acc[mt][nt][r] = 0.f;

#pragma unroll
    for (int ks = 0; ks < 8; ++ks) {
        const int o = ks * 8 + quad * 2;
        float4 a0 = frowA[o], a1 = frowA[o + 1];
        float4 b0 = frowB[o], b1 = frowB[o + 1];
        bfrag afA = pack8(a0, a1);
        bfrag afB = pack8(b0, b1);
#pragma unroll
        for (int nt = 0; nt < 4; ++nt) {
            bfrag bf = *(const bfrag*)&Wl[(((ks * 4 + nt) * 64) + lane) * 8];
            acc[0][nt] = __builtin_amdgcn_mfma_f32_16x16x32_bf16(afA, bf, acc[0][nt], 0, 0, 0);
            acc[1][nt] = __builtin_amdgcn_mfma_f32_16x16x32_bf16(afB, bf, acc[1][nt], 0, 0, 0);
        }
    }

#pragma unroll
    for (int mt = 0; mt < 2; ++mt) {
#pragma unroll
        for (int nt = 0; nt < 4; ++nt) {
            float bv = bias[nt * 16 + lc];
#pragma unroll
            for (int r = 0; r < 4; ++r) {
                int orow = rowbase + mt * 16 + quad * 4 + r;
                if (orow < n) {
                    float v = fmaxf(acc[mt][nt][r] + bv, 0.f);
                    out[(size_t)orow * OUT_CH + nt * 16 + lc] = f2bf(v);
                }
            }
        }
    }
}

// ---------------------------------------------------------------------------
// CSR build: XCD-bound work-ticket kernels. Block reads its true XCC id and
// drains its own group's chunk tickets first (L2-local cnt/cursor/spack),
// then steals from other groups (correctness under any dispatch mapping).
// ---------------------------------------------------------------------------
__global__ __launch_bounds__(256) void hist_kernel(
    const int* __restrict__ rows, int* __restrict__ cnt, int* __restrict__ tickets,
    int nEdges, int rpg, int nchunks)
{
    const unsigned myg = read_xcc_id();
    __shared__ int s_t;
    for (int gg = 0; gg < NGROUP; ++gg) {
        const int g  = (myg + gg) & (NGROUP - 1);
        const int lo = g * rpg, hi = lo + rpg;
        for (;;) {
            if (threadIdx.x == 0) s_t = atomicAdd(&tickets[g], 1);
            __syncthreads();
            const int t = s_t;
            if (t >= nchunks) break;
            const int base = t * ECHUNK + (int)threadIdx.x * 4;
            if (base + 3 < nEdges) {
                int4v r = __builtin_nontemporal_load((const int4v*)(rows + base));
                if (r.x >= lo && r.x < hi) atomicAdd(&cnt[r.x], 1);
                if (r.y >= lo && r.y < hi) atomicAdd(&cnt[r.y], 1);
                if (r.z >= lo && r.z < hi) atomicAdd(&cnt[r.z], 1);
                if (r.w >= lo && r.w < hi) atomicAdd(&cnt[r.w], 1);
            } else {
                for (int e = base; e < nEdges; ++e) {
                    int r = rows[e];
                    if (r >= lo && r < hi) atomicAdd(&cnt[r], 1);
                }
            }
            __syncthreads();
        }
    }
}

__global__ __launch_bounds__(256) void scatter_edges_kernel(
    const int* __restrict__ rows, const int* __restrict__ cols,
    const float* __restrict__ vals, int* __restrict__ cursor,
    int2* __restrict__ spack, int* __restrict__ tickets,
    int nEdges, int rpg, int nchunks, int aligned)
{
    const unsigned myg = read_xcc_id();
    __shared__ int s_t;
    for (int gg = 0; gg < NGROUP; ++gg) {
        const int g  = (myg + gg) & (NGROUP - 1);
        const int lo = g * rpg, hi = lo + rpg;
        for (;;) {
            if (threadIdx.x == 0) s_t = atomicAdd(&tickets[g], 1);
            __syncthreads();
            const int t = s_t;
            if (t >= nchunks) break;
            const int base = t * ECHUNK + (int)threadIdx.x * 4;
            if (aligned && base + 3 < nEdges) {
                int4v   r = __builtin_nontemporal_load((const int4v*)(rows + base));
                int4v   c = __builtin_nontemporal_load((const int4v*)(cols + base));
                float4v v = __builtin_nontemporal_load((const float4v*)(vals + base));
                if (r.x >= lo && r.x < hi) { int p = atomicAdd(&cursor[r.x], 1); spack[p] = make_int2(c.x, __float_as_int(v.x)); }
                if (r.y >= lo && r.y < hi) { int p = atomicAdd(&cursor[r.y], 1); spack[p] = make_int2(c.y, __float_as_int(v.y)); }
                if (r.z >= lo && r.z < hi) { int p = atomicAdd(&cursor[r.z], 1); spack[p] = make_int2(c.z, __float_as_int(v.z)); }
                if (r.w >= lo && r.w < hi) { int p = atomicAdd(&cursor[r.w], 1); spack[p] = make_int2(c.w, __float_as_int(v.w)); }
            } else {
                int e_end = min(base + 4, nEdges);
                for (int e = base; e < e_end; ++e) {
                    int r = rows[e];
                    if (r >= lo && r < hi) {
                        int p = atomicAdd(&cursor[r], 1);
                        spack[p] = make_int2(cols[e], __float_as_int(vals[e]));
                    }
                }
            }
            __syncthreads();
        }
    }
}

// ---------------------------------------------------------------------------
// two-level exclusive scan (unchanged)
// ---------------------------------------------------------------------------
__global__ __launch_bounds__(256) void block_sum_kernel(
    const int* __restrict__ cnt, int* __restrict__ blockSums, int n)
{
    __shared__ int ls[256];
    int t = threadIdx.x;
    int base = blockIdx.x * SCAN_CHUNK + t * 4;
    int s = 0;
#pragma unroll
    for (int j = 0; j < 4; ++j) {
        int i = base + j;
        if (i < n) s += cnt[i];
    }
    ls[t] = s;
    __syncthreads();
    for (int off = 128; off > 0; off >>= 1) {
        if (t < off) ls[t] += ls[t + off];
        __syncthreads();
    }
    if (t == 0) blockSums[blockIdx.x] = ls[0];
}

__global__ void scan_sums_kernel(int* __restrict__ blockSums, int nb,
                                 int* __restrict__ rowptr, int n, int total)
{
    int run = 0;
    for (int i = 0; i < nb; ++i) {
        int c = blockSums[i];
        blockSums[i] = run;
        run += c;
    }
    rowptr[n] = total;
}

__global__ __launch_bounds__(256) void scan_final_kernel(
    const int* __restrict__ cnt, const int* __restrict__ blockSums,
    int* __restrict__ rowptr, int* __restrict__ cursor, int n)
{
    __shared__ int ls[256];
    int t = threadIdx.x;
    int base = blockIdx.x * SCAN_CHUNK + t * 4;
    int v0 = (base + 0 < n) ? cnt[base + 0] : 0;
    int v1 = (base + 1 < n) ? cnt[base + 1] : 0;
    int v2 = (base + 2 < n) ? cnt[base + 2] : 0;
    int v3 = (base + 3 < n) ? cnt[base + 3] : 0;
    ls[t] = v0 + v1 + v2 + v3;
    __syncthreads();
    for (int off = 1; off < 256; off <<= 1) {
        int x = (t >= off) ? ls[t - off] : 0;
        __syncthreads();
        ls[t] += x;
        __syncthreads();
    }
    int prefix = blockSums[blockIdx.x] + (t ? ls[t - 1] : 0);
    int e0 = prefix;
    int e1 = e0 + v0;
    int e2 = e1 + v1;
    int e3 = e2 + v2;
    if (base + 0 < n) { rowptr[base + 0] = e0; cursor[base + 0] = e0; }
    if (base + 1 < n) { rowptr[base + 1] = e1; cursor[base + 1] = e1; }
    if (base + 2 < n) { rowptr[base + 2] = e2; cursor[base + 2] = e2; }
    if (base + 3 < n) { rowptr[base + 3] = e3; cursor[base + 3] = e3; }
}

// ---------------------------------------------------------------------------
// CSR SpMM hop, bf16 src: TWO rows per wave, 16 edges in flight per row
// (8 independent spack->gather chains per wave). fp32 accumulate, xor-reduce,
// lanes 0-15 store rowA / 16-31 store rowB (one coalesced 512 B store pair).
// ---------------------------------------------------------------------------
#define HOP_BODY(P, S, V, ACC)                                                \
    {                                                                         \
        float4 sf;                                                            \
        sf.x = bf2f(S.x); sf.y = bf2f(S.y); sf.z = bf2f(S.z); sf.w = bf2f(S.w);\
        ACC.x = fmaf(V, sf.x, ACC.x); ACC.y = fmaf(V, sf.y, ACC.y);           \
        ACC.z = fmaf(V, sf.z, ACC.z); ACC.w = fmaf(V, sf.w, ACC.w);           \
    }

template<bool DST_F32>
__global__ __launch_bounds__(256) void spmm_csr_kernel(
    const int* __restrict__ rowptr, const int2* __restrict__ spack,
    const unsigned short* __restrict__ src, void* __restrict__ dstv, int n)
{
    const int wv   = threadIdx.x >> 6;
    const int lane = threadIdx.x & 63;
    const int rowA = blockIdx.x * 8 + wv * 2;
    if (rowA >= n) return;
    const int rowB = rowA + 1;

    const int begA = rowptr[rowA];
    const int endA = rowptr[rowA + 1];
    int begB = 0, endB = 0;
    if (rowB < n) { begB = endA; endB = rowptr[rowB + 1]; }

    const int sub = lane >> 4;
    const int ch  = (lane & 15) * 4;

    float4 aA0 = make_float4(0.f, 0.f, 0.f, 0.f), aA1 = aA0;
    float4 aB0 = aA0, aB1 = aA0;

    int bA = begA, bB = begB;
    while (bA < endA || bB < endB) {
        int eA0 = bA + sub, eA1 = bA + 4 + sub, eA2 = bA + 8 + sub, eA3 = bA + 12 + sub;
        int eB0 = bB + sub, eB1 = bB + 4 + sub;
        int2 pA0 = spack[max(min(eA0, endA - 1), 0)];
        int2 pA1 = spack[max(min(eA1, endA - 1), 0)];
        int2 pA2 = spack[max(min(eA2, endA - 1), 0)];
        int2 pA3 = spack[max(min(eA3, endA - 1), 0)];
        int2 pB0 = spack[max(min(eB0, endB - 1), 0)];
        int2 pB1 = spack[max(min(eB1, endB - 1), 0)];
        float vA0 = (eA0 < endA) ? __int_as_float(pA0.y) : 0.f;
        float vA1 = (eA1 < endA) ? __int_as_float(pA1.y) : 0.f;
        float vA2 = (eA2 < endA) ? __int_as_float(pA2.y) : 0.f;
        float vA3 = (eA3 < endA) ? __int_as_float(pA3.y) : 0.f;
        float vB0 = (eB0 < endB) ? __int_as_float(pB0.y) : 0.f;
        float vB1 = (eB1 < endB) ? __int_as_float(pB1.y) : 0.f;
        ushort4 sA0 = *(const ushort4*)(src + ((size_t)pA0.x << 6) + ch);
        ushort4 sA1 = *(const ushort4*)(src + ((size_t)pA1.x << 6) + ch);
        ushort4 sA2 = *(const ushort4*)(src + ((size_t)pA2.x << 6) + ch);
        ushort4 sA3 = *(const ushort4*)(src + ((size_t)pA3.x << 6) + ch);
        ushort4 sB0 = *(const ushort4*)(src + ((size_t)pB0.x << 6) + ch);
        ushort4 sB1 = *(const ushort4*)(src + ((size_t)pB1.x << 6) + ch);
        HOP_BODY(pA0, sA0, vA0, aA0)
        HOP_BODY(pA1, sA1, vA1, aA1)
        HOP_BODY(pA2, sA2, vA2, aA0)
        HOP_BODY(pA3, sA3, vA3, aA1)
        HOP_BODY(pB0, sB0, vB0, aB0)
        HOP_BODY(pB1, sB1, vB1, aB1)
        bA += 16;
        bB += 8;
    }

    float4 accA = make_float4(aA0.x + aA1.x, aA0.y + aA1.y, aA0.z + aA1.z, aA0.w + aA1.w);
    float4 accB = make_float4(aB0.x + aB1.x, aB0.y + aB1.y, aB0.z + aB1.z, aB0.w + aB1.w);

#pragma unroll
    for (int mask = 16; mask <= 32; mask <<= 1) {
        accA.x += __shfl_xor(accA.x, mask);
        accA.y += __shfl_xor(accA.y, mask);
        accA.z += __shfl_xor(accA.z, mask);
        accA.w += __shfl_xor(accA.w, mask);
        accB.x += __shfl_xor(accB.x, mask);
        accB.y += __shfl_xor(accB.y, mask);
        accB.z += __shfl_xor(accB.z, mask);
        accB.w += __shfl_xor(accB.w, mask);
    }

    if (lane < 16) {
        if constexpr (DST_F32) {
            *(float4*)((float*)dstv + ((size_t)rowA << 6) + ch) = accA;
        } else {
            ushort4 o;
            o.x = f2bf(accA.x); o.y = f2bf(accA.y);
            o.z = f2bf(accA.z); o.w = f2bf(accA.w);
            *(ushort4*)((unsigned short*)dstv + ((size_t)rowA << 6) + ch) = o;
        }
    } else if (lane < 32 && rowB < n) {
        if constexpr (DST_F32) {
            *(float4*)((float*)dstv + ((size_t)rowB << 6) + ch) = accB;
        } else {
            ushort4 o;
            o.x = f2bf(accB.x); o.y = f2bf(accB.y);
            o.z = f2bf(accB.z); o.w = f2bf(accB.w);
            *(ushort4*)((unsigned short*)dstv + ((size_t)rowB << 6) + ch) = o;
        }
    }
}

// ---------------------------------------------------------------------------
extern "C" void kernel_launch(void* const* d_in, const int* in_sizes, int n_in,
                              void* d_out, int out_size, void* d_ws, size_t ws_size,
                              hipStream_t stream)
{
    const int*   adj  = (const int*)d_in[0];    // [2, E] int32
    const float* vals = (const float*)d_in[1];  // [E]
    const float* feat = (const float*)d_in[2];  // [N, 256]
    const float* W    = (const float*)d_in[3];  // [256, 64]
    const float* bias = (const float*)d_in[4];  // [1, 64]

    const int E = in_sizes[1];
    const int n = in_sizes[2] / IN_CH;
    const int* rows = adj;
    const int* cols = adj + E;

    char* ws = (char*)d_ws;
    size_t off = 0;
    auto alloc = [&](size_t bytes) {
        void* p = ws + off;
        off += (bytes + 255) & ~(size_t)255;
        return p;
    };
    unsigned short* B0 = (unsigned short*)alloc((size_t)n * OUT_CH * sizeof(unsigned short));
    unsigned short* B1 = (unsigned short*)alloc((size_t)n * OUT_CH * sizeof(unsigned short));
    int*   rowptr    = (int*)  alloc((size_t)(n + 1) * sizeof(int));
    int*   cursor    = (int*)  alloc((size_t)n * sizeof(int));
    int2*  spack     = (int2*) alloc((size_t)E * sizeof(int2));
    int*   blockSums = (int*)  alloc(4096 * sizeof(int));
    int*   tickets   = (int*)  alloc(16 * sizeof(int));   // [0..7] hist, [8..15] scatter

    float* out = (float*)d_out;

    const int rpg     = (n + NGROUP - 1) / NGROUP;
    const int nchunks = (E + ECHUNK - 1) / ECHUNK;
    const int aligned = ((((uintptr_t)cols) | ((uintptr_t)vals)) & 15) == 0;

    hipMemsetAsync(cursor, 0, (size_t)n * sizeof(int), stream);
    hipMemsetAsync(tickets, 0, 16 * sizeof(int), stream);

    hist_kernel<<<2048, 256, 0, stream>>>(rows, cursor, tickets, E, rpg, nchunks);

    const int nb = (n + SCAN_CHUNK - 1) / SCAN_CHUNK;
    block_sum_kernel<<<nb, 256, 0, stream>>>(cursor, blockSums, n);
    scan_sums_kernel<<<1, 1, 0, stream>>>(blockSums, nb, rowptr, n, E);
    scan_final_kernel<<<nb, 256, 0, stream>>>(cursor, blockSums, rowptr, cursor, n);
    scatter_edges_kernel<<<2048, 256, 0, stream>>>(rows, cols, vals, cursor, spack,
                                                   tickets + 8, E, rpg, nchunks, aligned);

    gemm_mfma_kernel<<<(n + 127) / 128, 256, 0, stream>>>(feat, W, bias, B0, n);

    const int hblocks = (n + 7) / 8;
    spmm_csr_kernel<false><<<hblocks, 256, 0, stream>>>(rowptr, spack, B0, B1, n);
    spmm_csr_kernel<false><<<hblocks, 256, 0, stream>>>(rowptr, spack, B1, B0, n);
    spmm_csr_kernel<true><<<hblocks, 256, 0, stream>>>(rowptr, spack, B0, out, n);
}